// Round 7
// baseline (75.436 us; speedup 1.0000x reference)
//
#include <hip/hip_runtime.h>
#include <hip/hip_bf16.h>

// SelfContrastiveLoss: loss over E = exp(qn @ kn^T / T), B=8192, D=256.
// R7: high-TLP simple structure — 128x128 tile, 4 waves (64x64 wave-tile,
//     acc=64 regs -> ~150 total/wave -> 3 blocks/CU = 12 waves/CU), single-
//     buffered 32KB LDS, plain 2-barrier K-loop (TLP hides latency, not hand
//     pipelining). Epilogue atomics eliminated: per-block partials to global
//     (RowP/ColP), summed in kernel 3.
//
// ws layout: qn bf16 4MB | kn bf16 4MB | diag 32KB | RowP 2MB | ColP 2MB

#define NB 8192
#define ND 256

constexpr float EPS = 1e-5f;
// exp(x*20) == exp2(x * 20*log2(e))
constexpr float EXP2_SCALE = 28.853900817779268f;

typedef float f32x4 __attribute__((ext_vector_type(4)));
typedef short s16x8 __attribute__((ext_vector_type(8)));

#define GLOAD_LDS16(g, l)                                                  \
  __builtin_amdgcn_global_load_lds(                                        \
      (const __attribute__((address_space(1))) unsigned int*)(g),          \
      (__attribute__((address_space(3))) unsigned int*)(l), 16, 0, 0)

// ---------------- kernel 1: row L2-normalize -> bf16, fp32 diag --------------
__global__ __launch_bounds__(256) void norm_diag_kernel(
    const float* __restrict__ q, const float* __restrict__ k,
    ushort* __restrict__ qn, ushort* __restrict__ kn, float* __restrict__ diag,
    float* __restrict__ out) {
  if (blockIdx.x == 0 && threadIdx.x == 0) out[0] = 0.f;  // loss accumulator

  const int wave = threadIdx.x >> 6;
  const int lane = threadIdx.x & 63;
  const int row = blockIdx.x * 4 + wave;          // one wave per row
  const float4* q4 = reinterpret_cast<const float4*>(q + (size_t)row * ND);
  const float4* k4 = reinterpret_cast<const float4*>(k + (size_t)row * ND);
  float4 qv = q4[lane];
  float4 kv = k4[lane];
  float sq = qv.x * qv.x + qv.y * qv.y + qv.z * qv.z + qv.w * qv.w;
  float sk = kv.x * kv.x + kv.y * kv.y + kv.z * kv.z + kv.w * kv.w;
  float dp = qv.x * kv.x + qv.y * kv.y + qv.z * kv.z + qv.w * kv.w;
#pragma unroll
  for (int m = 1; m < 64; m <<= 1) {
    sq += __shfl_xor(sq, m);
    sk += __shfl_xor(sk, m);
    dp += __shfl_xor(dp, m);
  }
  const float iq = 1.0f / fmaxf(sqrtf(sq), 1e-12f);   // F.normalize eps
  const float ik = 1.0f / fmaxf(sqrtf(sk), 1e-12f);
  union { ushort4 u; __hip_bfloat16 h[4]; } pq, pk;
  pq.h[0] = __float2bfloat16(qv.x * iq);
  pq.h[1] = __float2bfloat16(qv.y * iq);
  pq.h[2] = __float2bfloat16(qv.z * iq);
  pq.h[3] = __float2bfloat16(qv.w * iq);
  pk.h[0] = __float2bfloat16(kv.x * ik);
  pk.h[1] = __float2bfloat16(kv.y * ik);
  pk.h[2] = __float2bfloat16(kv.z * ik);
  pk.h[3] = __float2bfloat16(kv.w * ik);
  reinterpret_cast<ushort4*>(qn)[(size_t)row * (ND / 4) + lane] = pq.u;
  reinterpret_cast<ushort4*>(kn)[(size_t)row * (ND / 4) + lane] = pk.u;
  if (lane == 0) diag[row] = __expf(dp * iq * ik * 20.0f);  // exact fp32 diag
}

// ---------------- kernel 2: fused bf16 MFMA GEMM + exp + row/col partials ----
// 128x128 tile, 4 waves (2Mx2N of 64x64), acc[4][4] (64 f32). BK=64 single-
// buffered LDS 32KB -> 3 blocks/CU at ~150 regs. Chunk swizzle c^(r&7)
// (verified 0-conflict in R3-R6). No atomics: partials to RowP/ColP.
#define BT 128

__global__ __launch_bounds__(256, 3) void gemm_exp_reduce_kernel(
    const ushort* __restrict__ qn, const ushort* __restrict__ kn,
    float* __restrict__ RowP, float* __restrict__ ColP) {
  __shared__ ushort As[128 * 64];   // 16KB
  __shared__ ushort Bs[128 * 64];   // 16KB

  const int tid  = threadIdx.x;
  const int lane = tid & 63;
  const int wave = tid >> 6;          // 4 waves: 2M x 2N of 64x64
  const int wr = wave >> 1;
  const int wc = wave & 1;
  const int l15 = lane & 15;
  const int lhi = lane >> 4;

  // XCD-region map: 4096 blocks; xcd=(2x4) region of 32x16 tiles (~3MB < L2)
  const int lid = blockIdx.y * 64 + blockIdx.x;
  const int xcd = lid & 7;
  const int j   = lid >> 3;                       // 0..511
  const int rb  = (xcd >> 2) * 32 + (j >> 4);     // row-block 0..63
  const int cb  = (xcd & 3) * 16 + (j & 15);      // col-block 0..63
  const int brow = rb * BT;
  const int bcol = cb * BT;

  f32x4 acc[4][4];
#pragma unroll
  for (int mf = 0; mf < 4; ++mf)
#pragma unroll
    for (int nf = 0; nf < 4; ++nf)
      acc[mf][nf] = (f32x4){0.f, 0.f, 0.f, 0.f};

  for (int kt = 0; kt < 4; ++kt) {
    // stage A,B 128x64 tiles; 1024 chunks each, 4/thread; swizzled source
#pragma unroll
    for (int p = 0; p < 4; ++p) {
      const int f   = p * 256 + tid;
      const int row = f >> 3;
      const int gch = (f & 7) ^ (row & 7);
      GLOAD_LDS16(&qn[(size_t)(brow + row) * ND + kt * 64 + gch * 8],
                  As + (size_t)f * 8);
      GLOAD_LDS16(&kn[(size_t)(bcol + row) * ND + kt * 64 + gch * 8],
                  Bs + (size_t)f * 8);
    }
    __syncthreads();    // compiler drains vmcnt before s_barrier
#pragma unroll
    for (int ks = 0; ks < 2; ++ks) {
      s16x8 af[4], bf[4];
#pragma unroll
      for (int mf = 0; mf < 4; ++mf) {
        const int r = wr * 64 + mf * 16 + l15;
        af[mf] = *reinterpret_cast<const s16x8*>(
            As + r * 64 + ((ks * 4 + lhi) ^ (r & 7)) * 8);
      }
#pragma unroll
      for (int nf = 0; nf < 4; ++nf) {
        const int r = wc * 64 + nf * 16 + l15;
        bf[nf] = *reinterpret_cast<const s16x8*>(
            Bs + r * 64 + ((ks * 4 + lhi) ^ (r & 7)) * 8);
      }
#pragma unroll
      for (int mf = 0; mf < 4; ++mf)
#pragma unroll
        for (int nf = 0; nf < 4; ++nf)
          acc[mf][nf] = __builtin_amdgcn_mfma_f32_16x16x32_bf16(
              af[mf], bf[nf], acc[mf][nf], 0, 0, 0);
    }
    __syncthreads();
  }

  // ---- epilogue: E = exp2(S*scale); partial row/col sums; no atomics ----
#pragma unroll
  for (int mf = 0; mf < 4; ++mf)
#pragma unroll
    for (int nf = 0; nf < 4; ++nf)
#pragma unroll
      for (int j2 = 0; j2 < 4; ++j2)
        acc[mf][nf][j2] = exp2f(acc[mf][nf][j2] * EXP2_SCALE);

  float* RS = reinterpret_cast<float*>(As);   // [128][3] row partials (wc 0/1)
  float* CS = reinterpret_cast<float*>(Bs);   // [128][9] col partials (8 used)

  // row partials: C/D layout col=lane&15, row=(lane>>4)*4+j
#pragma unroll
  for (int mf = 0; mf < 4; ++mf) {
#pragma unroll
    for (int j2 = 0; j2 < 4; ++j2) {
      float v = acc[mf][0][j2] + acc[mf][1][j2] + acc[mf][2][j2] + acc[mf][3][j2];
      v += __shfl_xor(v, 1);
      v += __shfl_xor(v, 2);
      v += __shfl_xor(v, 4);
      v += __shfl_xor(v, 8);
      if (l15 == 0)
        RS[(wr * 64 + mf * 16 + lhi * 4 + j2) * 3 + wc] = v;
    }
  }
  // col partials: per col one value per (wr,lhi)
#pragma unroll
  for (int nf = 0; nf < 4; ++nf) {
    f32x4 s4 = acc[0][nf] + acc[1][nf] + acc[2][nf] + acc[3][nf];
    const float cs = s4[0] + s4[1] + s4[2] + s4[3];
    CS[(wc * 64 + nf * 16 + l15) * 9 + wr * 4 + lhi] = cs;
  }
  __syncthreads();
  if (tid < 128) {
    const float rp = RS[tid * 3 + 0] + RS[tid * 3 + 1];
    RowP[(size_t)cb * NB + brow + tid] = rp;
  } else {
    const int t = tid - 128;
    const float* c = &CS[t * 9];
    const float cp = ((c[0] + c[1]) + (c[2] + c[3])) +
                     ((c[4] + c[5]) + (c[6] + c[7]));
    ColP[(size_t)rb * NB + bcol + t] = cp;
  }
}

// ---------------- kernel 3: sum partials + final scalar loss ----------------
__global__ __launch_bounds__(256) void loss_kernel(
    const float* __restrict__ diag, const float* __restrict__ RowP,
    const float* __restrict__ ColP, float* __restrict__ out) {
  const int i = blockIdx.x * 256 + threadIdx.x;   // 32 blocks x 256 = 8192
  float rs = 0.f, cs = 0.f;
#pragma unroll 8
  for (int j = 0; j < 64; ++j) {
    rs += RowP[(size_t)j * NB + i];
    cs += ColP[(size_t)j * NB + i];
  }
  const float d = diag[i];
  float acc = -__logf(d / rs + EPS) - __logf(d / cs + EPS);
#pragma unroll
  for (int m = 1; m < 64; m <<= 1) acc += __shfl_xor(acc, m);
  __shared__ float ls[4];
  const int wave = threadIdx.x >> 6;
  if ((threadIdx.x & 63) == 0) ls[wave] = acc;
  __syncthreads();
  if (threadIdx.x == 0)
    atomicAdd(out, (ls[0] + ls[1] + ls[2] + ls[3]) * (1.0f / NB));
}

extern "C" void kernel_launch(void* const* d_in, const int* in_sizes, int n_in,
                              void* d_out, int out_size, void* d_ws, size_t ws_size,
                              hipStream_t stream) {
  const float* q = (const float*)d_in[0];
  const float* k = (const float*)d_in[1];
  char* ws = (char*)d_ws;
  ushort* qn   = (ushort*)ws;                                   // 4 MB
  ushort* kn   = (ushort*)(ws + (size_t)NB * ND * 2);           // 4 MB
  float*  diag = (float*)(ws + (size_t)NB * ND * 4);            // 32 KB
  float*  RowP = diag + NB;                                     // 2 MB
  float*  ColP = RowP + 64 * NB;                                // 2 MB
  float*  out = (float*)d_out;

  norm_diag_kernel<<<NB / 4, 256, 0, stream>>>(q, k, qn, kn, diag, out);
  gemm_exp_reduce_kernel<<<dim3(64, 64), 256, 0, stream>>>(qn, kn, RowP, ColP);
  loss_kernel<<<32, 256, 0, stream>>>(diag, RowP, ColP, out);
}

// Round 9
// 66.808 us; speedup vs baseline: 1.1291x; 1.1291x over previous
//
#include <hip/hip_runtime.h>
#include <hip/hip_bf16.h>

// SelfContrastiveLoss: loss over E = exp(qn @ kn^T / T), B=8192, D=256.
// R9: R8 (MX-fp8 single-stage GEMM) with the colsum-partial race fixed:
//     CS index must include lhi (4 lanes hold different row-quarters of the
//     same column) — CS[(col)*9 + wr*4 + lhi], summed over 8 slots.
//
// ws layout: qn8 2MB | kn8 2MB | diag 32KB | RowP 2MB | ColP 2MB

#define NB 8192
#define ND 256

constexpr float EPS = 1e-5f;
// exp(x*20) == exp2(x * 20*log2(e))
constexpr float EXP2_SCALE = 28.853900817779268f;

typedef float f32x4 __attribute__((ext_vector_type(4)));
typedef int   i32x4 __attribute__((ext_vector_type(4)));
typedef int   i32x8 __attribute__((ext_vector_type(8)));

#define GLOAD_LDS16(g, l)                                                  \
  __builtin_amdgcn_global_load_lds(                                        \
      (const __attribute__((address_space(1))) unsigned int*)(g),          \
      (__attribute__((address_space(3))) unsigned int*)(l), 16, 0, 0)

// ---------------- kernel 1: row L2-normalize -> fp8 e4m3, fp32 diag ----------
__global__ __launch_bounds__(256) void norm_diag_kernel(
    const float* __restrict__ q, const float* __restrict__ k,
    uint* __restrict__ qn8, uint* __restrict__ kn8, float* __restrict__ diag,
    float* __restrict__ out) {
  if (blockIdx.x == 0 && threadIdx.x == 0) out[0] = 0.f;  // loss accumulator

  const int wave = threadIdx.x >> 6;
  const int lane = threadIdx.x & 63;
  const int row = blockIdx.x * 4 + wave;          // one wave per row
  const float4* q4 = reinterpret_cast<const float4*>(q + (size_t)row * ND);
  const float4* k4 = reinterpret_cast<const float4*>(k + (size_t)row * ND);
  float4 qv = q4[lane];
  float4 kv = k4[lane];
  float sq = qv.x * qv.x + qv.y * qv.y + qv.z * qv.z + qv.w * qv.w;
  float sk = kv.x * kv.x + kv.y * kv.y + kv.z * kv.z + kv.w * kv.w;
  float dp = qv.x * kv.x + qv.y * kv.y + qv.z * kv.z + qv.w * kv.w;
#pragma unroll
  for (int m = 1; m < 64; m <<= 1) {
    sq += __shfl_xor(sq, m);
    sk += __shfl_xor(sk, m);
    dp += __shfl_xor(dp, m);
  }
  const float iq = 1.0f / fmaxf(sqrtf(sq), 1e-12f);   // F.normalize eps
  const float ik = 1.0f / fmaxf(sqrtf(sk), 1e-12f);
  // pack 4 normalized f32 -> 4 fp8 e4m3 (OCP) in one dword
  int dq = __builtin_amdgcn_cvt_pk_fp8_f32(qv.x * iq, qv.y * iq, 0, false);
  dq = __builtin_amdgcn_cvt_pk_fp8_f32(qv.z * iq, qv.w * iq, dq, true);
  int dk = __builtin_amdgcn_cvt_pk_fp8_f32(kv.x * ik, kv.y * ik, 0, false);
  dk = __builtin_amdgcn_cvt_pk_fp8_f32(kv.z * ik, kv.w * ik, dk, true);
  qn8[(size_t)row * 64 + lane] = (uint)dq;
  kn8[(size_t)row * 64 + lane] = (uint)dk;
  if (lane == 0) diag[row] = __expf(dp * iq * ik * 20.0f);  // exact fp32 diag
}

// ---------------- kernel 2: MX-fp8 MFMA GEMM + exp + row/col partials --------
// 128x128 tile, 8 waves (2M x 4N, wave-tile 64x32), acc[4][2] (32 f32).
// LDS: As 128x256B + Bs 128x256B = 64KB, staged ONCE (full K=256).
// Swizzle: 16B unit u of row r stored from global unit u^(r&15) (involution);
// reads apply the same XOR -> 2-way max bank aliasing (free).
#define BT 128

__global__ __launch_bounds__(512, 4) void gemm_exp_reduce_kernel(
    const char* __restrict__ qn8, const char* __restrict__ kn8,
    float* __restrict__ RowP, float* __restrict__ ColP) {
  extern __shared__ char smem[];     // 64 KB
  char* As = smem;                   // [128][256] bytes
  char* Bs = smem + 32768;

  const int tid  = threadIdx.x;
  const int lane = tid & 63;
  const int wave = tid >> 6;          // 8 waves: 2M x 4N
  const int wr = wave >> 2;           // 0..1  (64-row strip)
  const int wc = wave & 3;            // 0..3  (32-col strip)
  const int l15 = lane & 15;
  const int lhi = lane >> 4;

  // XCD-region map: 4096 blocks; xcd region of 32x16 tiles (~3MB < 4MB L2)
  const int lid = blockIdx.y * 64 + blockIdx.x;
  const int xcd = lid & 7;
  const int j   = lid >> 3;                       // 0..511
  const int rb  = (xcd >> 2) * 32 + (j >> 4);     // row-block 0..63
  const int cb  = (xcd & 3) * 16 + (j & 15);      // col-block 0..63
  const int brow = rb * BT;
  const int bcol = cb * BT;

  // ---- stage full 128x256B of A and B: 2048 16B units each, 4/thread ----
#pragma unroll
  for (int p = 0; p < 4; ++p) {
    const int f   = p * 512 + tid;      // 0..2047
    const int row = f >> 4;             // 0..127
    const int su  = (f & 15) ^ (row & 15);   // inverse-swizzled source unit
    GLOAD_LDS16(qn8 + (size_t)(brow + row) * ND + su * 16, As + (size_t)f * 16);
    GLOAD_LDS16(kn8 + (size_t)(bcol + row) * ND + su * 16, Bs + (size_t)f * 16);
  }
  __syncthreads();                      // vmcnt(0) drain + barrier (once!)

  f32x4 acc[4][2];
#pragma unroll
  for (int mf = 0; mf < 4; ++mf)
#pragma unroll
    for (int nf = 0; nf < 2; ++nf)
      acc[mf][nf] = (f32x4){0.f, 0.f, 0.f, 0.f};

  // frag load: row r, K-chunk C = ks*4+lhi (32B = logical units 2C,2C+1);
  // physical unit = logical ^ (r&15); r&15 == l15 for all frag rows.
  auto ldfrag = [&](const char* base, int r, int ks) -> i32x8 {
    const int u0 = ((ks * 8 + lhi * 2) ^ l15) * 16;
    const int u1 = ((ks * 8 + lhi * 2 + 1) ^ l15) * 16;
    i32x4 lo = *reinterpret_cast<const i32x4*>(base + r * 256 + u0);
    i32x4 hi = *reinterpret_cast<const i32x4*>(base + r * 256 + u1);
    i32x8 v;
    v[0] = lo[0]; v[1] = lo[1]; v[2] = lo[2]; v[3] = lo[3];
    v[4] = hi[0]; v[5] = hi[1]; v[6] = hi[2]; v[7] = hi[3];
    return v;
  };

#pragma unroll
  for (int ks = 0; ks < 2; ++ks) {
    const i32x8 b0 = ldfrag(Bs, wc * 32 + l15, ks);
    const i32x8 b1 = ldfrag(Bs, wc * 32 + 16 + l15, ks);
#pragma unroll
    for (int mf = 0; mf < 4; ++mf) {
      const i32x8 a = ldfrag(As, wr * 64 + mf * 16 + l15, ks);
      // fp8(e4m3) x fp8: cbsz=0, blgp=0; unity e8m0 scales (0x7F = 2^0)
      acc[mf][0] = __builtin_amdgcn_mfma_scale_f32_16x16x128_f8f6f4(
          a, b0, acc[mf][0], 0, 0, 0, 0x7F7F7F7F, 0, 0x7F7F7F7F);
      acc[mf][1] = __builtin_amdgcn_mfma_scale_f32_16x16x128_f8f6f4(
          a, b1, acc[mf][1], 0, 0, 0, 0x7F7F7F7F, 0, 0x7F7F7F7F);
    }
  }

  // ---- epilogue: E = exp2(S*scale); row/col partials; no atomics ----
#pragma unroll
  for (int mf = 0; mf < 4; ++mf)
#pragma unroll
    for (int nf = 0; nf < 2; ++nf)
#pragma unroll
      for (int j2 = 0; j2 < 4; ++j2)
        acc[mf][nf][j2] = exp2f(acc[mf][nf][j2] * EXP2_SCALE);

  __syncthreads();                      // all LDS frag reads done; reuse smem
  float* RS = reinterpret_cast<float*>(smem);   // [128][5] row partials by wc
  float* CS = RS + 128 * 5;                     // [128][9] col partials by wr*4+lhi

  // C/D layout (shape-determined, m127/m128): col = lane&15, row = lhi*4+j2
#pragma unroll
  for (int mf = 0; mf < 4; ++mf) {
#pragma unroll
    for (int j2 = 0; j2 < 4; ++j2) {
      float v = acc[mf][0][j2] + acc[mf][1][j2];   // sum this wave's 32 cols
      v += __shfl_xor(v, 1);
      v += __shfl_xor(v, 2);
      v += __shfl_xor(v, 4);
      v += __shfl_xor(v, 8);
      if (l15 == 0)
        RS[(wr * 64 + mf * 16 + lhi * 4 + j2) * 5 + wc] = v;
    }
  }
  // col partials: lane (l15, lhi) of wave (wr,wc) holds rows {lhi*4+j2} of each
  // 16-block -> per (col, wr) there are 4 DISTINCT lhi contributions (R8 bug:
  // these raced on one slot). Index by wr*4+lhi.
#pragma unroll
  for (int nf = 0; nf < 2; ++nf) {
    f32x4 s4 = acc[0][nf] + acc[1][nf] + acc[2][nf] + acc[3][nf];
    CS[(wc * 32 + nf * 16 + l15) * 9 + wr * 4 + lhi] =
        s4[0] + s4[1] + s4[2] + s4[3];
  }
  __syncthreads();
  if (tid < 128) {
    const float rp = RS[tid * 5 + 0] + RS[tid * 5 + 1] +
                     RS[tid * 5 + 2] + RS[tid * 5 + 3];
    RowP[(size_t)cb * NB + brow + tid] = rp;
  } else if (tid < 256) {
    const int t = tid - 128;
    const float* c = &CS[t * 9];
    ColP[(size_t)rb * NB + bcol + t] =
        ((c[0] + c[1]) + (c[2] + c[3])) + ((c[4] + c[5]) + (c[6] + c[7]));
  }
}

// ---------------- kernel 3: sum partials + final scalar loss ----------------
__global__ __launch_bounds__(256) void loss_kernel(
    const float* __restrict__ diag, const float* __restrict__ RowP,
    const float* __restrict__ ColP, float* __restrict__ out) {
  const int i = blockIdx.x * 256 + threadIdx.x;   // 32 blocks x 256 = 8192
  float rs = 0.f, cs = 0.f;
#pragma unroll 8
  for (int j = 0; j < 64; ++j) {
    rs += RowP[(size_t)j * NB + i];
    cs += ColP[(size_t)j * NB + i];
  }
  const float d = diag[i];
  float acc = -__logf(d / rs + EPS) - __logf(d / cs + EPS);
#pragma unroll
  for (int m = 1; m < 64; m <<= 1) acc += __shfl_xor(acc, m);
  __shared__ float ls[4];
  const int wave = threadIdx.x >> 6;
  if ((threadIdx.x & 63) == 0) ls[wave] = acc;
  __syncthreads();
  if (threadIdx.x == 0)
    atomicAdd(out, (ls[0] + ls[1] + ls[2] + ls[3]) * (1.0f / NB));
}

extern "C" void kernel_launch(void* const* d_in, const int* in_sizes, int n_in,
                              void* d_out, int out_size, void* d_ws, size_t ws_size,
                              hipStream_t stream) {
  const float* q = (const float*)d_in[0];
  const float* k = (const float*)d_in[1];
  char* ws = (char*)d_ws;
  uint*  qn8  = (uint*)ws;                                      // 2 MB
  uint*  kn8  = (uint*)(ws + (size_t)NB * ND);                  // 2 MB
  float* diag = (float*)(ws + (size_t)2 * NB * ND);             // 32 KB
  float* RowP = diag + NB;                                      // 2 MB
  float* ColP = RowP + 64 * NB;                                 // 2 MB
  float* out  = (float*)d_out;

  (void)hipFuncSetAttribute((const void*)gemm_exp_reduce_kernel,
                            hipFuncAttributeMaxDynamicSharedMemorySize, 65536);

  norm_diag_kernel<<<NB / 4, 256, 0, stream>>>(q, k, qn8, kn8, diag, out);
  gemm_exp_reduce_kernel<<<dim3(64, 64), 512, 65536, stream>>>(
      (const char*)qn8, (const char*)kn8, RowP, ColP);
  loss_kernel<<<32, 256, 0, stream>>>(diag, RowP, ColP, out);
}

// Round 10
// 65.049 us; speedup vs baseline: 1.1597x; 1.0270x over previous
//
#include <hip/hip_runtime.h>
#include <hip/hip_bf16.h>

// SelfContrastiveLoss: loss over E = exp(qn @ kn^T / T), B=8192, D=256.
// R10: NO operand LDS. Norm kernel writes a fragment-packed fp8 layout
//      (per 16-row group: unit p = ks*128 + b*64 + lane holds row g*16+(lane&15),
//      K-bytes ks*128+(lane>>4)*32+b*16). GEMM loads fragments L2->registers
//      with one coalesced dwordx4 per lane per unit (base + lane*16), 16 MFMA,
//      single barrier (epilogue combine). Data is L2-resident; staging it in
//      LDS was pure overhead (R9: MfmaUtil 12% = MFMA floor, VALU/latency rest).
//
// ws layout: qp 2MB | kp 2MB | diag 32KB | RowP 2MB | ColP 2MB

#define NB 8192
#define ND 256

constexpr float EPS = 1e-5f;
// exp(x*20) == exp2(x * 20*log2(e))
constexpr float EXP2_SCALE = 28.853900817779268f;

typedef float f32x4 __attribute__((ext_vector_type(4)));
typedef int   i32x4 __attribute__((ext_vector_type(4)));
typedef int   i32x8 __attribute__((ext_vector_type(8)));

// ------------- kernel 1: L2-normalize -> fp8 e4m3 packed, fp32 diag ----------
// 512 blocks x 1024 threads; wave w handles row blockIdx*16+w; LDS transpose
// pass re-emits the 16-row group in fragment-packed order (coalesced 4KB).
__global__ __launch_bounds__(1024) void norm_pack_kernel(
    const float* __restrict__ q, const float* __restrict__ k,
    uint* __restrict__ qp, uint* __restrict__ kp, float* __restrict__ diag,
    float* __restrict__ out) {
  __shared__ uint lq[16 * 64];   // [row][dword] 16 rows x 256B
  __shared__ uint lk[16 * 64];
  if (blockIdx.x == 0 && threadIdx.x == 0) out[0] = 0.f;  // loss accumulator

  const int w    = threadIdx.x >> 6;          // 0..15 row-in-group
  const int lane = threadIdx.x & 63;
  const int row  = blockIdx.x * 16 + w;
  const float4* q4 = reinterpret_cast<const float4*>(q + (size_t)row * ND);
  const float4* k4 = reinterpret_cast<const float4*>(k + (size_t)row * ND);
  float4 qv = q4[lane];
  float4 kv = k4[lane];
  float sq = qv.x * qv.x + qv.y * qv.y + qv.z * qv.z + qv.w * qv.w;
  float sk = kv.x * kv.x + kv.y * kv.y + kv.z * kv.z + kv.w * kv.w;
  float dp = qv.x * kv.x + qv.y * kv.y + qv.z * kv.z + qv.w * kv.w;
#pragma unroll
  for (int m = 1; m < 64; m <<= 1) {
    sq += __shfl_xor(sq, m);
    sk += __shfl_xor(sk, m);
    dp += __shfl_xor(dp, m);
  }
  const float iq = 1.0f / fmaxf(sqrtf(sq), 1e-12f);   // F.normalize eps
  const float ik = 1.0f / fmaxf(sqrtf(sk), 1e-12f);
  int dq = __builtin_amdgcn_cvt_pk_fp8_f32(qv.x * iq, qv.y * iq, 0, false);
  dq = __builtin_amdgcn_cvt_pk_fp8_f32(qv.z * iq, qv.w * iq, dq, true);
  int dk = __builtin_amdgcn_cvt_pk_fp8_f32(kv.x * ik, kv.y * ik, 0, false);
  dk = __builtin_amdgcn_cvt_pk_fp8_f32(kv.z * ik, kv.w * ik, dk, true);
  lq[w * 64 + lane] = (uint)dq;
  lk[w * 64 + lane] = (uint)dk;
  if (lane == 0) diag[row] = __expf(dp * iq * ik * 20.0f);  // exact fp32 diag
  __syncthreads();

  // packed write: unit p = ks*128 + b*64 + (lhi*16+l15) holds
  // row l15, K-bytes ks*128 + lhi*32 + b*16.
  const int t = threadIdx.x;
  if (t < 512) {
    const int u   = t & 255;
    const int ks  = u >> 7;
    const int b   = (u >> 6) & 1;
    const int lp  = u & 63;
    const int lhi = lp >> 4, l15 = lp & 15;
    const int src_dw = l15 * 64 + ks * 32 + lhi * 8 + b * 4;
    const uint* Ls = (t < 256) ? lq : lk;
    uint4 v = *reinterpret_cast<const uint4*>(&Ls[src_dw]);
    uint* dst = (t < 256) ? qp : kp;
    reinterpret_cast<uint4*>(dst)[(size_t)blockIdx.x * 256 + u] = v;
  }
}

// ------------- kernel 2: MX-fp8 MFMA GEMM (no operand LDS) + exp + partials --
// 128x128 tile, 8 waves (2M x 4N, wave-tile 64x32), acc[4][2] (32 f32).
// Fragments loaded straight from packed global (L2) -> registers.
#define BT 128

__global__ __launch_bounds__(512, 4) void gemm_exp_reduce_kernel(
    const uint* __restrict__ qp, const uint* __restrict__ kp,
    float* __restrict__ RowP, float* __restrict__ ColP) {
  __shared__ float RS[128 * 5];   // row partials by wc
  __shared__ float CS[128 * 9];   // col partials by wr*4+lhi

  const int tid  = threadIdx.x;
  const int lane = tid & 63;
  const int wave = tid >> 6;          // 8 waves: 2M x 4N
  const int wr = wave >> 2;           // 0..1  (64-row strip)
  const int wc = wave & 3;            // 0..3  (32-col strip)
  const int l15 = lane & 15;
  const int lhi = lane >> 4;

  // XCD-region map: 4096 blocks; xcd region of 32x16 tiles (~1.5MB < 4MB L2)
  const int lid = blockIdx.y * 64 + blockIdx.x;
  const int xcd = lid & 7;
  const int j   = lid >> 3;                       // 0..511
  const int rb  = (xcd >> 2) * 32 + (j >> 4);     // row-block 0..63
  const int cb  = (xcd & 3) * 16 + (j & 15);      // col-block 0..63
  const int brow = rb * BT;
  const int bcol = cb * BT;

  // packed unit pointers for this block's row/col groups
  const uint4* Ag = reinterpret_cast<const uint4*>(qp) + ((size_t)(brow >> 4) + wr * 4) * 256;
  const uint4* Bg = reinterpret_cast<const uint4*>(kp) + ((size_t)(bcol >> 4) + wc * 2) * 256;

  f32x4 acc[4][2];
#pragma unroll
  for (int mf = 0; mf < 4; ++mf)
#pragma unroll
    for (int nf = 0; nf < 2; ++nf)
      acc[mf][nf] = (f32x4){0.f, 0.f, 0.f, 0.f};

  auto ldu = [&](const uint4* g, int unit) -> i32x4 {
    return *reinterpret_cast<const i32x4*>(&g[unit + lane]);
  };
  auto cat = [](i32x4 lo, i32x4 hi) -> i32x8 {
    i32x8 v;
    v[0] = lo[0]; v[1] = lo[1]; v[2] = lo[2]; v[3] = lo[3];
    v[4] = hi[0]; v[5] = hi[1]; v[6] = hi[2]; v[7] = hi[3];
    return v;
  };

#pragma unroll
  for (int ks = 0; ks < 2; ++ks) {
    const i32x8 b0 = cat(ldu(Bg, ks * 128), ldu(Bg, ks * 128 + 64));
    const i32x8 b1 = cat(ldu(Bg, 256 + ks * 128), ldu(Bg, 256 + ks * 128 + 64));
#pragma unroll
    for (int mf = 0; mf < 4; ++mf) {
      const i32x8 a = cat(ldu(Ag, mf * 256 + ks * 128),
                          ldu(Ag, mf * 256 + ks * 128 + 64));
      // fp8(e4m3) x fp8; unity e8m0 scales (0x7F = 2^0)
      acc[mf][0] = __builtin_amdgcn_mfma_scale_f32_16x16x128_f8f6f4(
          a, b0, acc[mf][0], 0, 0, 0, 0x7F7F7F7F, 0, 0x7F7F7F7F);
      acc[mf][1] = __builtin_amdgcn_mfma_scale_f32_16x16x128_f8f6f4(
          a, b1, acc[mf][1], 0, 0, 0, 0x7F7F7F7F, 0, 0x7F7F7F7F);
    }
  }

  // ---- epilogue: E = exp2(S*scale); row/col partials; no atomics ----
#pragma unroll
  for (int mf = 0; mf < 4; ++mf)
#pragma unroll
    for (int nf = 0; nf < 2; ++nf)
#pragma unroll
      for (int j2 = 0; j2 < 4; ++j2)
        acc[mf][nf][j2] = exp2f(acc[mf][nf][j2] * EXP2_SCALE);

  // C/D layout (shape-determined): col = lane&15, row = lhi*4+j2
#pragma unroll
  for (int mf = 0; mf < 4; ++mf) {
#pragma unroll
    for (int j2 = 0; j2 < 4; ++j2) {
      float v = acc[mf][0][j2] + acc[mf][1][j2];   // this wave's 32 cols
      v += __shfl_xor(v, 1);
      v += __shfl_xor(v, 2);
      v += __shfl_xor(v, 4);
      v += __shfl_xor(v, 8);
      if (l15 == 0)
        RS[(wr * 64 + mf * 16 + lhi * 4 + j2) * 5 + wc] = v;
    }
  }
  // col partials: per (col, wr) 4 distinct lhi contributions (R8 lesson)
#pragma unroll
  for (int nf = 0; nf < 2; ++nf) {
    f32x4 s4 = acc[0][nf] + acc[1][nf] + acc[2][nf] + acc[3][nf];
    CS[(wc * 32 + nf * 16 + l15) * 9 + wr * 4 + lhi] =
        s4[0] + s4[1] + s4[2] + s4[3];
  }
  __syncthreads();
  if (tid < 128) {
    const float rp = RS[tid * 5 + 0] + RS[tid * 5 + 1] +
                     RS[tid * 5 + 2] + RS[tid * 5 + 3];
    RowP[(size_t)cb * NB + brow + tid] = rp;
  } else if (tid < 256) {
    const int t = tid - 128;
    const float* c = &CS[t * 9];
    ColP[(size_t)rb * NB + bcol + t] =
        ((c[0] + c[1]) + (c[2] + c[3])) + ((c[4] + c[5]) + (c[6] + c[7]));
  }
}

// ---------------- kernel 3: sum partials + final scalar loss ----------------
__global__ __launch_bounds__(256) void loss_kernel(
    const float* __restrict__ diag, const float* __restrict__ RowP,
    const float* __restrict__ ColP, float* __restrict__ out) {
  const int i = blockIdx.x * 256 + threadIdx.x;   // 32 blocks x 256 = 8192
  float rs = 0.f, cs = 0.f;
#pragma unroll 8
  for (int j = 0; j < 64; ++j) {
    rs += RowP[(size_t)j * NB + i];
    cs += ColP[(size_t)j * NB + i];
  }
  const float d = diag[i];
  float acc = -__logf(d / rs + EPS) - __logf(d / cs + EPS);
#pragma unroll
  for (int m = 1; m < 64; m <<= 1) acc += __shfl_xor(acc, m);
  __shared__ float ls[4];
  const int wave = threadIdx.x >> 6;
  if ((threadIdx.x & 63) == 0) ls[wave] = acc;
  __syncthreads();
  if (threadIdx.x == 0)
    atomicAdd(out, (ls[0] + ls[1] + ls[2] + ls[3]) * (1.0f / NB));
}

extern "C" void kernel_launch(void* const* d_in, const int* in_sizes, int n_in,
                              void* d_out, int out_size, void* d_ws, size_t ws_size,
                              hipStream_t stream) {
  const float* q = (const float*)d_in[0];
  const float* k = (const float*)d_in[1];
  char* ws = (char*)d_ws;
  uint*  qp   = (uint*)ws;                                      // 2 MB packed
  uint*  kp   = (uint*)(ws + (size_t)NB * ND);                  // 2 MB packed
  float* diag = (float*)(ws + (size_t)2 * NB * ND);             // 32 KB
  float* RowP = diag + NB;                                      // 2 MB
  float* ColP = RowP + 64 * NB;                                 // 2 MB
  float* out  = (float*)d_out;

  norm_pack_kernel<<<NB / 16, 1024, 0, stream>>>(q, k, qp, kp, diag, out);
  gemm_exp_reduce_kernel<<<dim3(64, 64), 512, 0, stream>>>(qp, kp, RowP, ColP);
  loss_kernel<<<32, 256, 0, stream>>>(diag, RowP, ColP, out);
}

// Round 11
// 55.040 us; speedup vs baseline: 1.3706x; 1.1818x over previous
//
#include <hip/hip_runtime.h>
#include <hip/hip_bf16.h>

// SelfContrastiveLoss: loss over E = exp(qn @ kn^T / T), B=8192, D=256.
// R11: VALU/DS-diet GEMM. (1) 32B-per-lane contiguous packing -> i32x8 frag
//      loads compile to 2 adjacent dwordx4, no concat movs. (2) transposed
//      MFMA mfma(K,Q): rowsum becomes in-thread adds + 2 shfl; colsum via
//      4-stage fold transpose-reduce (8 shfl). Epilogue DS ~75 -> ~24/thread.
//      R9/R10 showed loads don't bind (3x L2 traffic, same time) — VALU/DS do.
//
// ws layout: qp 2MB | kp 2MB | diag 32KB | RowP 2MB | ColP 2MB

#define NB 8192
#define ND 256

constexpr float EPS = 1e-5f;
// exp(x*20) == exp2(x * 20*log2(e))
constexpr float EXP2_SCALE = 28.853900817779268f;

typedef float f32x4 __attribute__((ext_vector_type(4)));
typedef int   i32x8 __attribute__((ext_vector_type(8)));

// packed layout (per 16-row group g, per matrix): unit (ks, lane) = 32 bytes:
//   row g*16 + (lane&15), K-bytes ks*128 + (lane>>4)*32 .. +32, CONTIGUOUS.
// address: byte = g*4096 + ks*2048 + lane*32.

// ------------- kernel 1: L2-normalize -> fp8 e4m3 packed, fp32 diag ----------
__global__ __launch_bounds__(1024) void norm_pack_kernel(
    const float* __restrict__ q, const float* __restrict__ k,
    uint* __restrict__ qp, uint* __restrict__ kp, float* __restrict__ diag,
    float* __restrict__ out) {
  __shared__ uint lq[16 * 68];   // stride 68 dwords: breaks 64-stride banks
  __shared__ uint lk[16 * 68];
  if (blockIdx.x == 0 && threadIdx.x == 0) out[0] = 0.f;  // loss accumulator

  const int w    = threadIdx.x >> 6;          // 0..15 row-in-group
  const int lane = threadIdx.x & 63;
  const int row  = blockIdx.x * 16 + w;
  const float4* q4 = reinterpret_cast<const float4*>(q + (size_t)row * ND);
  const float4* k4 = reinterpret_cast<const float4*>(k + (size_t)row * ND);
  float4 qv = q4[lane];
  float4 kv = k4[lane];
  float sq = qv.x * qv.x + qv.y * qv.y + qv.z * qv.z + qv.w * qv.w;
  float sk = kv.x * kv.x + kv.y * kv.y + kv.z * kv.z + kv.w * kv.w;
  float dp = qv.x * kv.x + qv.y * kv.y + qv.z * kv.z + qv.w * kv.w;
#pragma unroll
  for (int m = 1; m < 64; m <<= 1) {
    sq += __shfl_xor(sq, m);
    sk += __shfl_xor(sk, m);
    dp += __shfl_xor(dp, m);
  }
  const float iq = 1.0f / fmaxf(sqrtf(sq), 1e-12f);   // F.normalize eps
  const float ik = 1.0f / fmaxf(sqrtf(sk), 1e-12f);
  int dq = __builtin_amdgcn_cvt_pk_fp8_f32(qv.x * iq, qv.y * iq, 0, false);
  dq = __builtin_amdgcn_cvt_pk_fp8_f32(qv.z * iq, qv.w * iq, dq, true);
  int dk = __builtin_amdgcn_cvt_pk_fp8_f32(kv.x * ik, kv.y * ik, 0, false);
  dk = __builtin_amdgcn_cvt_pk_fp8_f32(kv.z * ik, kv.w * ik, dk, true);
  lq[w * 68 + lane] = (uint)dq;
  lk[w * 68 + lane] = (uint)dk;
  if (lane == 0) diag[row] = __expf(dp * iq * ik * 20.0f);  // exact fp32 diag
  __syncthreads();

  // packed write: thread t<512 handles one 16B half of one 32B unit.
  const int t = threadIdx.x;
  if (t < 512) {
    const int tt = t & 255;
    const int u  = tt >> 1;           // unit 0..127 (= ks*64 + lane)
    const int h  = tt & 1;            // 16B half
    const int ul = u & 63;            // unit lane
    const int ks = u >> 6;
    const int src_dw = (ul & 15) * 68 + ks * 32 + (ul >> 4) * 8 + h * 4;
    const uint* Ls = (t < 256) ? lq : lk;
    uint4 v = *reinterpret_cast<const uint4*>(&Ls[src_dw]);
    uint* dst = (t < 256) ? qp : kp;
    reinterpret_cast<uint4*>(dst)[(size_t)blockIdx.x * 256 + tt] = v;
  }
}

// ------------- kernel 2: MX-fp8 MFMA GEMM (transposed) + exp + partials ------
// 128x128 tile, 8 waves (2 q-half x 4 k-quarter), wave-tile 64 qrows x 32 kcols.
// TRANSPOSED compute: acc = mfma(K, Q) -> D[row=kcol][col=qrow]:
//   at lane (l15,lhi), frag (kg,qg), elem j2:
//   S[qrow = brow+wr*64+qg*16+l15][kcol = bcol+wc*32+kg*16+lhi*4+j2]
#define BT 128

__global__ __launch_bounds__(512, 4) void gemm_exp_reduce_kernel(
    const uint* __restrict__ qp, const uint* __restrict__ kp,
    float* __restrict__ RowP, float* __restrict__ ColP) {
  __shared__ float RS[128 * 5];   // row partials by wc (4 used)
  __shared__ float CS[128 * 3];   // col partials by wr (2 used)

  const int tid  = threadIdx.x;
  const int lane = tid & 63;
  const int wave = tid >> 6;
  const int wr = wave >> 2;           // 0..1  (64 q-rows)
  const int wc = wave & 3;            // 0..3  (32 k-cols)
  const int l15 = lane & 15;
  const int lhi = lane >> 4;

  // XCD-region map: 4096 blocks; xcd region of 32x16 tiles
  const int lid = blockIdx.y * 64 + blockIdx.x;
  const int xcd = lid & 7;
  const int j   = lid >> 3;                       // 0..511
  const int rb  = (xcd >> 2) * 32 + (j >> 4);     // row-block 0..63
  const int cb  = (xcd & 3) * 16 + (j & 15);      // col-block 0..63
  const int brow = rb * BT;
  const int bcol = cb * BT;

  const i32x8* qp8 = reinterpret_cast<const i32x8*>(qp);
  const i32x8* kp8 = reinterpret_cast<const i32x8*>(kp);
  // i32x8 index: g*128 + ks*64 + lane
  const int qg0 = (brow >> 4) + wr * 4;   // 4 q-groups for this wave
  const int kg0 = (bcol >> 4) + wc * 2;   // 2 k-groups

  f32x4 acc[2][4];   // [kg][qg]
#pragma unroll
  for (int kg = 0; kg < 2; ++kg)
#pragma unroll
    for (int qg = 0; qg < 4; ++qg)
      acc[kg][qg] = (f32x4){0.f, 0.f, 0.f, 0.f};

  // K fragments stay live (4 x i32x8)
  i32x8 kf[2][2];
#pragma unroll
  for (int kg = 0; kg < 2; ++kg)
#pragma unroll
    for (int ks = 0; ks < 2; ++ks)
      kf[kg][ks] = kp8[(size_t)(kg0 + kg) * 128 + ks * 64 + lane];

#pragma unroll
  for (int qg = 0; qg < 4; ++qg) {
    i32x8 qf0 = qp8[(size_t)(qg0 + qg) * 128 + 0 * 64 + lane];
    i32x8 qf1 = qp8[(size_t)(qg0 + qg) * 128 + 1 * 64 + lane];
#pragma unroll
    for (int kg = 0; kg < 2; ++kg) {
      // fp8 x fp8, unity e8m0 scales (0x7F = 2^0); A=K, B=Q (transposed)
      acc[kg][qg] = __builtin_amdgcn_mfma_scale_f32_16x16x128_f8f6f4(
          kf[kg][0], qf0, acc[kg][qg], 0, 0, 0, 0x7F7F7F7F, 0, 0x7F7F7F7F);
      acc[kg][qg] = __builtin_amdgcn_mfma_scale_f32_16x16x128_f8f6f4(
          kf[kg][1], qf1, acc[kg][qg], 0, 0, 0, 0x7F7F7F7F, 0, 0x7F7F7F7F);
    }
  }

  // ---- E = exp2(S*scale) ----
#pragma unroll
  for (int kg = 0; kg < 2; ++kg)
#pragma unroll
    for (int qg = 0; qg < 4; ++qg)
#pragma unroll
      for (int j2 = 0; j2 < 4; ++j2)
        acc[kg][qg][j2] = exp2f(acc[kg][qg][j2] * EXP2_SCALE);

  // ---- rowsums (q-rows): in-thread over kg,j2 (7 adds), fold over lhi ----
  float rs[4];
#pragma unroll
  for (int qg = 0; qg < 4; ++qg) {
    f32x4 s4 = acc[0][qg] + acc[1][qg];
    float v = (s4[0] + s4[1]) + (s4[2] + s4[3]);
    v += __shfl_xor(v, 16);
    v += __shfl_xor(v, 32);
    rs[qg] = v;   // full 32-col sum for row (qg, l15), replicated over lhi
  }
  // lane (l15, lhi) writes row wr*64 + lhi*16 + l15 using rs[lhi]
  {
    float val = (lhi == 0) ? rs[0] : (lhi == 1) ? rs[1] : (lhi == 2) ? rs[2] : rs[3];
    RS[(wr * 64 + lhi * 16 + l15) * 5 + wc] = val;
  }

  // ---- colsums (k-cols): in-thread over qg, then 4-stage fold over l15 ----
  // c[kg][j2] = partial over this thread's 4 q-rows
  float c0[4], c1[4];
#pragma unroll
  for (int j2 = 0; j2 < 4; ++j2) {
    c0[j2] = (acc[0][0][j2] + acc[0][1][j2]) + (acc[0][2][j2] + acc[0][3][j2]);
    c1[j2] = (acc[1][0][j2] + acc[1][1][j2]) + (acc[1][2][j2] + acc[1][3][j2]);
  }
  const bool b0 = (l15 & 1), b1 = (l15 & 2), b2 = (l15 & 4);
  // stage 1 (xor 1): fold j2 bit0
  float d00, d01, d10, d11;
  {
    float t, u;
    t = b0 ? c0[0] : c0[1]; u = __shfl_xor(t, 1); d00 = (b0 ? c0[1] : c0[0]) + u;
    t = b0 ? c0[2] : c0[3]; u = __shfl_xor(t, 1); d01 = (b0 ? c0[3] : c0[2]) + u;
    t = b0 ? c1[0] : c1[1]; u = __shfl_xor(t, 1); d10 = (b0 ? c1[1] : c1[0]) + u;
    t = b0 ? c1[2] : c1[3]; u = __shfl_xor(t, 1); d11 = (b0 ? c1[3] : c1[2]) + u;
  }
  // stage 2 (xor 2): fold j2 bit1
  float e0, e1;
  {
    float t, u;
    t = b1 ? d00 : d01; u = __shfl_xor(t, 2); e0 = (b1 ? d01 : d00) + u;
    t = b1 ? d10 : d11; u = __shfl_xor(t, 2); e1 = (b1 ? d11 : d10) + u;
  }
  // stage 3 (xor 4): fold kg
  float f;
  {
    float t = b2 ? e0 : e1;
    float u = __shfl_xor(t, 4);
    f = (b2 ? e1 : e0) + u;
  }
  // stage 4 (xor 8): plain reduce (both halves end equal)
  f += __shfl_xor(f, 8);
  // lane (l15 = dup*8 + kg*4 + j2, lhi): kcol = wc*32 + kg*16 + lhi*4 + j2
  if (l15 < 8) {
    const int kcol = wc * 32 + (l15 >> 2) * 16 + lhi * 4 + (l15 & 3);
    CS[kcol * 3 + wr] = f;
  }
  __syncthreads();

  if (tid < 128) {
    const float* r = &RS[tid * 5];
    RowP[(size_t)cb * NB + brow + tid] = (r[0] + r[1]) + (r[2] + r[3]);
  } else if (tid < 256) {
    const int t = tid - 128;
    ColP[(size_t)rb * NB + bcol + t] = CS[t * 3 + 0] + CS[t * 3 + 1];
  }
}

// ---------------- kernel 3: sum partials + final scalar loss ----------------
__global__ __launch_bounds__(256) void loss_kernel(
    const float* __restrict__ diag, const float* __restrict__ RowP,
    const float* __restrict__ ColP, float* __restrict__ out) {
  const int i = blockIdx.x * 256 + threadIdx.x;   // 32 blocks x 256 = 8192
  float rs = 0.f, cs = 0.f;
#pragma unroll 8
  for (int j = 0; j < 64; ++j) {
    rs += RowP[(size_t)j * NB + i];
    cs += ColP[(size_t)j * NB + i];
  }
  const float d = diag[i];
  float acc = -__logf(d / rs + EPS) - __logf(d / cs + EPS);
#pragma unroll
  for (int m = 1; m < 64; m <<= 1) acc += __shfl_xor(acc, m);
  __shared__ float ls[4];
  const int wave = threadIdx.x >> 6;
  if ((threadIdx.x & 63) == 0) ls[wave] = acc;
  __syncthreads();
  if (threadIdx.x == 0)
    atomicAdd(out, (ls[0] + ls[1] + ls[2] + ls[3]) * (1.0f / NB));
}

extern "C" void kernel_launch(void* const* d_in, const int* in_sizes, int n_in,
                              void* d_out, int out_size, void* d_ws, size_t ws_size,
                              hipStream_t stream) {
  const float* q = (const float*)d_in[0];
  const float* k = (const float*)d_in[1];
  char* ws = (char*)d_ws;
  uint*  qp   = (uint*)ws;                                      // 2 MB packed
  uint*  kp   = (uint*)(ws + (size_t)NB * ND);                  // 2 MB packed
  float* diag = (float*)(ws + (size_t)2 * NB * ND);             // 32 KB
  float* RowP = diag + NB;                                      // 2 MB
  float* ColP = RowP + 64 * NB;                                 // 2 MB
  float* out  = (float*)d_out;

  norm_pack_kernel<<<NB / 16, 1024, 0, stream>>>(q, k, qp, kp, diag, out);
  gemm_exp_reduce_kernel<<<dim3(64, 64), 512, 0, stream>>>(qp, kp, RowP, ColP);
  loss_kernel<<<32, 256, 0, stream>>>(diag, RowP, ColP, out);
}

// Round 12
// 51.938 us; speedup vs baseline: 1.4524x; 1.0597x over previous
//
#include <hip/hip_runtime.h>
#include <hip/hip_bf16.h>

// SelfContrastiveLoss: loss over E = exp(qn @ kn^T / T), B=8192, D=256.
// R12: TLP push. R11 showed latency chains bind (epilogue diet saved 2.6x the
//      issue-cycle estimate). Reorder MFMA loop (ks outer) so only 2 K-frags
//      are held (peak regs ~80) and set __launch_bounds__(512,6) -> 6 waves/
//      SIMD (3 blocks/CU), +50% latency-hiding TLP. Everything else = R11.
//
// ws layout: qp 2MB | kp 2MB | diag 32KB | RowP 2MB | ColP 2MB

#define NB 8192
#define ND 256

constexpr float EPS = 1e-5f;
// exp(x*20) == exp2(x * 20*log2(e))
constexpr float EXP2_SCALE = 28.853900817779268f;

typedef float f32x4 __attribute__((ext_vector_type(4)));
typedef int   i32x8 __attribute__((ext_vector_type(8)));

// packed layout (per 16-row group g, per matrix): 32B unit (ks, lane):
//   row g*16 + (lane&15), K-bytes ks*128 + (lane>>4)*32 .. +32, CONTIGUOUS.
// byte address = g*4096 + ks*2048 + lane*32.

// ------------- kernel 1: L2-normalize -> fp8 e4m3 packed, fp32 diag ----------
__global__ __launch_bounds__(1024) void norm_pack_kernel(
    const float* __restrict__ q, const float* __restrict__ k,
    uint* __restrict__ qp, uint* __restrict__ kp, float* __restrict__ diag,
    float* __restrict__ out) {
  __shared__ uint lq[16 * 68];   // stride 68 dwords: breaks 64-stride banks
  __shared__ uint lk[16 * 68];
  if (blockIdx.x == 0 && threadIdx.x == 0) out[0] = 0.f;  // loss accumulator

  const int w    = threadIdx.x >> 6;          // 0..15 row-in-group
  const int lane = threadIdx.x & 63;
  const int row  = blockIdx.x * 16 + w;
  const float4* q4 = reinterpret_cast<const float4*>(q + (size_t)row * ND);
  const float4* k4 = reinterpret_cast<const float4*>(k + (size_t)row * ND);
  float4 qv = q4[lane];
  float4 kv = k4[lane];
  float sq = qv.x * qv.x + qv.y * qv.y + qv.z * qv.z + qv.w * qv.w;
  float sk = kv.x * kv.x + kv.y * kv.y + kv.z * kv.z + kv.w * kv.w;
  float dp = qv.x * kv.x + qv.y * kv.y + qv.z * kv.z + qv.w * kv.w;
#pragma unroll
  for (int m = 1; m < 64; m <<= 1) {
    sq += __shfl_xor(sq, m);
    sk += __shfl_xor(sk, m);
    dp += __shfl_xor(dp, m);
  }
  const float iq = 1.0f / fmaxf(sqrtf(sq), 1e-12f);   // F.normalize eps
  const float ik = 1.0f / fmaxf(sqrtf(sk), 1e-12f);
  int dq = __builtin_amdgcn_cvt_pk_fp8_f32(qv.x * iq, qv.y * iq, 0, false);
  dq = __builtin_amdgcn_cvt_pk_fp8_f32(qv.z * iq, qv.w * iq, dq, true);
  int dk = __builtin_amdgcn_cvt_pk_fp8_f32(kv.x * ik, kv.y * ik, 0, false);
  dk = __builtin_amdgcn_cvt_pk_fp8_f32(kv.z * ik, kv.w * ik, dk, true);
  lq[w * 68 + lane] = (uint)dq;
  lk[w * 68 + lane] = (uint)dk;
  if (lane == 0) diag[row] = __expf(dp * iq * ik * 20.0f);  // exact fp32 diag
  __syncthreads();

  // packed write: thread t<512 handles one 16B half of one 32B unit.
  const int t = threadIdx.x;
  if (t < 512) {
    const int tt = t & 255;
    const int u  = tt >> 1;           // unit 0..127 (= ks*64 + lane)
    const int h  = tt & 1;            // 16B half
    const int ul = u & 63;            // unit lane
    const int ks = u >> 6;
    const int src_dw = (ul & 15) * 68 + ks * 32 + (ul >> 4) * 8 + h * 4;
    const uint* Ls = (t < 256) ? lq : lk;
    uint4 v = *reinterpret_cast<const uint4*>(&Ls[src_dw]);
    uint* dst = (t < 256) ? qp : kp;
    reinterpret_cast<uint4*>(dst)[(size_t)blockIdx.x * 256 + tt] = v;
  }
}

// ------------- kernel 2: MX-fp8 MFMA GEMM (transposed) + exp + partials ------
// 128x128 tile, 8 waves (2 q-half x 4 k-quarter), wave-tile 64 qrows x 32 kcols.
// TRANSPOSED compute: acc = mfma(K, Q) -> D[row=kcol][col=qrow]:
//   at lane (l15,lhi), frag (kg,qg), elem j2:
//   S[qrow = brow+wr*64+qg*16+l15][kcol = bcol+wc*32+kg*16+lhi*4+j2]
#define BT 128

__global__ __launch_bounds__(512, 6) void gemm_exp_reduce_kernel(
    const uint* __restrict__ qp, const uint* __restrict__ kp,
    float* __restrict__ RowP, float* __restrict__ ColP) {
  __shared__ float RS[128 * 5];   // row partials by wc (4 used)
  __shared__ float CS[128 * 3];   // col partials by wr (2 used)

  const int tid  = threadIdx.x;
  const int lane = tid & 63;
  const int wave = tid >> 6;
  const int wr = wave >> 2;           // 0..1  (64 q-rows)
  const int wc = wave & 3;            // 0..3  (32 k-cols)
  const int l15 = lane & 15;
  const int lhi = lane >> 4;

  // XCD-region map: 4096 blocks; xcd region of 32x16 tiles
  const int lid = blockIdx.y * 64 + blockIdx.x;
  const int xcd = lid & 7;
  const int j   = lid >> 3;                       // 0..511
  const int rb  = (xcd >> 2) * 32 + (j >> 4);     // row-block 0..63
  const int cb  = (xcd & 3) * 16 + (j & 15);      // col-block 0..63
  const int brow = rb * BT;
  const int bcol = cb * BT;

  const i32x8* qp8 = reinterpret_cast<const i32x8*>(qp);
  const i32x8* kp8 = reinterpret_cast<const i32x8*>(kp);
  // i32x8 index: g*128 + ks*64 + lane
  const int qg0 = (brow >> 4) + wr * 4;   // 4 q-groups for this wave
  const int kg0 = (bcol >> 4) + wc * 2;   // 2 k-groups

  f32x4 acc[2][4];   // [kg][qg]
#pragma unroll
  for (int kg = 0; kg < 2; ++kg)
#pragma unroll
    for (int qg = 0; qg < 4; ++qg)
      acc[kg][qg] = (f32x4){0.f, 0.f, 0.f, 0.f};

  // ks outer: hold only 2 K-frags + 1 Q-frag live -> peak regs ~80
#pragma unroll
  for (int ks = 0; ks < 2; ++ks) {
    const i32x8 kf0 = kp8[(size_t)(kg0 + 0) * 128 + ks * 64 + lane];
    const i32x8 kf1 = kp8[(size_t)(kg0 + 1) * 128 + ks * 64 + lane];
#pragma unroll
    for (int qg = 0; qg < 4; ++qg) {
      const i32x8 qf = qp8[(size_t)(qg0 + qg) * 128 + ks * 64 + lane];
      // fp8 x fp8, unity e8m0 scales (0x7F = 2^0); A=K, B=Q (transposed)
      acc[0][qg] = __builtin_amdgcn_mfma_scale_f32_16x16x128_f8f6f4(
          kf0, qf, acc[0][qg], 0, 0, 0, 0x7F7F7F7F, 0, 0x7F7F7F7F);
      acc[1][qg] = __builtin_amdgcn_mfma_scale_f32_16x16x128_f8f6f4(
          kf1, qf, acc[1][qg], 0, 0, 0, 0x7F7F7F7F, 0, 0x7F7F7F7F);
    }
  }

  // ---- E = exp2(S*scale) ----
#pragma unroll
  for (int kg = 0; kg < 2; ++kg)
#pragma unroll
    for (int qg = 0; qg < 4; ++qg)
#pragma unroll
      for (int j2 = 0; j2 < 4; ++j2)
        acc[kg][qg][j2] = exp2f(acc[kg][qg][j2] * EXP2_SCALE);

  // ---- rowsums (q-rows): in-thread over kg,j2 (7 adds), fold over lhi ----
  float rs[4];
#pragma unroll
  for (int qg = 0; qg < 4; ++qg) {
    f32x4 s4 = acc[0][qg] + acc[1][qg];
    float v = (s4[0] + s4[1]) + (s4[2] + s4[3]);
    v += __shfl_xor(v, 16);
    v += __shfl_xor(v, 32);
    rs[qg] = v;   // full 32-col sum for row (qg, l15), replicated over lhi
  }
  // lane (l15, lhi) writes row wr*64 + lhi*16 + l15 using rs[lhi]
  {
    float val = (lhi == 0) ? rs[0] : (lhi == 1) ? rs[1] : (lhi == 2) ? rs[2] : rs[3];
    RS[(wr * 64 + lhi * 16 + l15) * 5 + wc] = val;
  }

  // ---- colsums (k-cols): in-thread over qg, then 4-stage fold over l15 ----
  float c0[4], c1[4];
#pragma unroll
  for (int j2 = 0; j2 < 4; ++j2) {
    c0[j2] = (acc[0][0][j2] + acc[0][1][j2]) + (acc[0][2][j2] + acc[0][3][j2]);
    c1[j2] = (acc[1][0][j2] + acc[1][1][j2]) + (acc[1][2][j2] + acc[1][3][j2]);
  }
  const bool b0 = (l15 & 1), b1 = (l15 & 2), b2 = (l15 & 4);
  // stage 1 (xor 1): fold j2 bit0
  float d00, d01, d10, d11;
  {
    float t, u;
    t = b0 ? c0[0] : c0[1]; u = __shfl_xor(t, 1); d00 = (b0 ? c0[1] : c0[0]) + u;
    t = b0 ? c0[2] : c0[3]; u = __shfl_xor(t, 1); d01 = (b0 ? c0[3] : c0[2]) + u;
    t = b0 ? c1[0] : c1[1]; u = __shfl_xor(t, 1); d10 = (b0 ? c1[1] : c1[0]) + u;
    t = b0 ? c1[2] : c1[3]; u = __shfl_xor(t, 1); d11 = (b0 ? c1[3] : c1[2]) + u;
  }
  // stage 2 (xor 2): fold j2 bit1
  float e0, e1;
  {
    float t, u;
    t = b1 ? d00 : d01; u = __shfl_xor(t, 2); e0 = (b1 ? d01 : d00) + u;
    t = b1 ? d10 : d11; u = __shfl_xor(t, 2); e1 = (b1 ? d11 : d10) + u;
  }
  // stage 3 (xor 4): fold kg
  float f;
  {
    float t = b2 ? e0 : e1;
    float u = __shfl_xor(t, 4);
    f = (b2 ? e1 : e0) + u;
  }
  // stage 4 (xor 8): plain reduce (both halves end equal)
  f += __shfl_xor(f, 8);
  // lane (l15 = dup*8 + kg*4 + j2, lhi): kcol = wc*32 + kg*16 + lhi*4 + j2
  if (l15 < 8) {
    const int kcol = wc * 32 + (l15 >> 2) * 16 + lhi * 4 + (l15 & 3);
    CS[kcol * 3 + wr] = f;
  }
  __syncthreads();

  if (tid < 128) {
    const float* r = &RS[tid * 5];
    RowP[(size_t)cb * NB + brow + tid] = (r[0] + r[1]) + (r[2] + r[3]);
  } else if (tid < 256) {
    const int t = tid - 128;
    ColP[(size_t)rb * NB + bcol + t] = CS[t * 3 + 0] + CS[t * 3 + 1];
  }
}

// ---------------- kernel 3: sum partials + final scalar loss ----------------
__global__ __launch_bounds__(256) void loss_kernel(
    const float* __restrict__ diag, const float* __restrict__ RowP,
    const float* __restrict__ ColP, float* __restrict__ out) {
  const int i = blockIdx.x * 256 + threadIdx.x;   // 32 blocks x 256 = 8192
  float rs = 0.f, cs = 0.f;
#pragma unroll 8
  for (int j = 0; j < 64; ++j) {
    rs += RowP[(size_t)j * NB + i];
    cs += ColP[(size_t)j * NB + i];
  }
  const float d = diag[i];
  float acc = -__logf(d / rs + EPS) - __logf(d / cs + EPS);
#pragma unroll
  for (int m = 1; m < 64; m <<= 1) acc += __shfl_xor(acc, m);
  __shared__ float ls[4];
  const int wave = threadIdx.x >> 6;
  if ((threadIdx.x & 63) == 0) ls[wave] = acc;
  __syncthreads();
  if (threadIdx.x == 0)
    atomicAdd(out, (ls[0] + ls[1] + ls[2] + ls[3]) * (1.0f / NB));
}

extern "C" void kernel_launch(void* const* d_in, const int* in_sizes, int n_in,
                              void* d_out, int out_size, void* d_ws, size_t ws_size,
                              hipStream_t stream) {
  const float* q = (const float*)d_in[0];
  const float* k = (const float*)d_in[1];
  char* ws = (char*)d_ws;
  uint*  qp   = (uint*)ws;                                      // 2 MB packed
  uint*  kp   = (uint*)(ws + (size_t)NB * ND);                  // 2 MB packed
  float* diag = (float*)(ws + (size_t)2 * NB * ND);             // 32 KB
  float* RowP = diag + NB;                                      // 2 MB
  float* ColP = RowP + 64 * NB;                                 // 2 MB
  float* out  = (float*)d_out;

  norm_pack_kernel<<<NB / 16, 1024, 0, stream>>>(q, k, qp, kp, diag, out);
  gemm_exp_reduce_kernel<<<dim3(64, 64), 512, 0, stream>>>(qp, kp, RowP, ColP);
  loss_kernel<<<32, 256, 0, stream>>>(diag, RowP, ColP, out);
}

// Round 13
// 48.672 us; speedup vs baseline: 1.5499x; 1.0671x over previous
//
#include <hip/hip_runtime.h>
#include <hip/hip_bf16.h>

// SelfContrastiveLoss: loss over E = exp(qn @ kn^T / T), B=8192, D=256.
// R13: L2-traffic cut. R12 analysis: operand path = 786 MB L2 (23 us floor)
//      with 64x32 wave-tiles (12 B/output). Move to 64x64 wave-tiles
//      (acc[4][4], 8 B/output -> 524 MB -> 15.2 us floor). 4-wave blocks
//      (128x128 tile), launch_bounds(256,4). Everything else = R12.
//
// ws layout: qp 2MB | kp 2MB | diag 32KB | RowP 2MB | ColP 2MB

#define NB 8192
#define ND 256

constexpr float EPS = 1e-5f;
// exp(x*20) == exp2(x * 20*log2(e))
constexpr float EXP2_SCALE = 28.853900817779268f;

typedef float f32x4 __attribute__((ext_vector_type(4)));
typedef int   i32x8 __attribute__((ext_vector_type(8)));

// packed layout (per 16-row group g, per matrix): 32B unit (ks, lane):
//   row g*16 + (lane&15), K-bytes ks*128 + (lane>>4)*32 .. +32, CONTIGUOUS.
// byte address = g*4096 + ks*2048 + lane*32.

// ------------- kernel 1: L2-normalize -> fp8 e4m3 packed, fp32 diag ----------
__global__ __launch_bounds__(1024) void norm_pack_kernel(
    const float* __restrict__ q, const float* __restrict__ k,
    uint* __restrict__ qp, uint* __restrict__ kp, float* __restrict__ diag,
    float* __restrict__ out) {
  __shared__ uint lq[16 * 68];   // stride 68 dwords: breaks 64-stride banks
  __shared__ uint lk[16 * 68];
  if (blockIdx.x == 0 && threadIdx.x == 0) out[0] = 0.f;  // loss accumulator

  const int w    = threadIdx.x >> 6;          // 0..15 row-in-group
  const int lane = threadIdx.x & 63;
  const int row  = blockIdx.x * 16 + w;
  const float4* q4 = reinterpret_cast<const float4*>(q + (size_t)row * ND);
  const float4* k4 = reinterpret_cast<const float4*>(k + (size_t)row * ND);
  float4 qv = q4[lane];
  float4 kv = k4[lane];
  float sq = qv.x * qv.x + qv.y * qv.y + qv.z * qv.z + qv.w * qv.w;
  float sk = kv.x * kv.x + kv.y * kv.y + kv.z * kv.z + kv.w * kv.w;
  float dp = qv.x * kv.x + qv.y * kv.y + qv.z * kv.z + qv.w * kv.w;
#pragma unroll
  for (int m = 1; m < 64; m <<= 1) {
    sq += __shfl_xor(sq, m);
    sk += __shfl_xor(sk, m);
    dp += __shfl_xor(dp, m);
  }
  const float iq = 1.0f / fmaxf(sqrtf(sq), 1e-12f);   // F.normalize eps
  const float ik = 1.0f / fmaxf(sqrtf(sk), 1e-12f);
  int dq = __builtin_amdgcn_cvt_pk_fp8_f32(qv.x * iq, qv.y * iq, 0, false);
  dq = __builtin_amdgcn_cvt_pk_fp8_f32(qv.z * iq, qv.w * iq, dq, true);
  int dk = __builtin_amdgcn_cvt_pk_fp8_f32(kv.x * ik, kv.y * ik, 0, false);
  dk = __builtin_amdgcn_cvt_pk_fp8_f32(kv.z * ik, kv.w * ik, dk, true);
  lq[w * 68 + lane] = (uint)dq;
  lk[w * 68 + lane] = (uint)dk;
  if (lane == 0) diag[row] = __expf(dp * iq * ik * 20.0f);  // exact fp32 diag
  __syncthreads();

  // packed write: thread t<512 handles one 16B half of one 32B unit.
  const int t = threadIdx.x;
  if (t < 512) {
    const int tt = t & 255;
    const int u  = tt >> 1;           // unit 0..127 (= ks*64 + lane)
    const int h  = tt & 1;            // 16B half
    const int ul = u & 63;            // unit lane
    const int ks = u >> 6;
    const int src_dw = (ul & 15) * 68 + ks * 32 + (ul >> 4) * 8 + h * 4;
    const uint* Ls = (t < 256) ? lq : lk;
    uint4 v = *reinterpret_cast<const uint4*>(&Ls[src_dw]);
    uint* dst = (t < 256) ? qp : kp;
    reinterpret_cast<uint4*>(dst)[(size_t)blockIdx.x * 256 + tt] = v;
  }
}

// ------------- kernel 2: MX-fp8 MFMA GEMM (transposed) + exp + partials ------
// 128x128 tile, 4 waves (2 q-half x 2 k-half), wave-tile 64 qrows x 64 kcols.
// TRANSPOSED compute: acc = mfma(K, Q) -> at lane (l15,lhi), frag (kg,qg), j2:
//   S[qrow = brow+wr*64+qg*16+l15][kcol = bcol+wc*64+kg*16+lhi*4+j2]
#define BT 128

__global__ __launch_bounds__(256, 4) void gemm_exp_reduce_kernel(
    const uint* __restrict__ qp, const uint* __restrict__ kp,
    float* __restrict__ RowP, float* __restrict__ ColP) {
  __shared__ float RS[128 * 3];   // row partials by wc (2 used)
  __shared__ float CS[128 * 3];   // col partials by wr (2 used)

  const int tid  = threadIdx.x;
  const int lane = tid & 63;
  const int wave = tid >> 6;
  const int wr = wave >> 1;           // 0..1  (64 q-rows)
  const int wc = wave & 1;            // 0..1  (64 k-cols)
  const int l15 = lane & 15;
  const int lhi = lane >> 4;

  // XCD-region map: 4096 blocks; xcd region of 32x16 tiles
  const int lid = blockIdx.y * 64 + blockIdx.x;
  const int xcd = lid & 7;
  const int j   = lid >> 3;                       // 0..511
  const int rb  = (xcd >> 2) * 32 + (j >> 4);     // row-block 0..63
  const int cb  = (xcd & 3) * 16 + (j & 15);      // col-block 0..63
  const int brow = rb * BT;
  const int bcol = cb * BT;

  const i32x8* qp8 = reinterpret_cast<const i32x8*>(qp);
  const i32x8* kp8 = reinterpret_cast<const i32x8*>(kp);
  // i32x8 index: g*128 + ks*64 + lane
  const int qg0 = (brow >> 4) + wr * 4;   // 4 q-groups for this wave
  const int kg0 = (bcol >> 4) + wc * 4;   // 4 k-groups

  f32x4 acc[4][4];   // [kg][qg]
#pragma unroll
  for (int kg = 0; kg < 4; ++kg)
#pragma unroll
    for (int qg = 0; qg < 4; ++qg)
      acc[kg][qg] = (f32x4){0.f, 0.f, 0.f, 0.f};

  // ks outer: hold 4 K-frags + 1 Q-frag live; peak regs ~115
#pragma unroll
  for (int ks = 0; ks < 2; ++ks) {
    i32x8 kf[4];
#pragma unroll
    for (int kg = 0; kg < 4; ++kg)
      kf[kg] = kp8[(size_t)(kg0 + kg) * 128 + ks * 64 + lane];
#pragma unroll
    for (int qg = 0; qg < 4; ++qg) {
      const i32x8 qf = qp8[(size_t)(qg0 + qg) * 128 + ks * 64 + lane];
#pragma unroll
      for (int kg = 0; kg < 4; ++kg)
        // fp8 x fp8, unity e8m0 scales (0x7F = 2^0); A=K, B=Q (transposed)
        acc[kg][qg] = __builtin_amdgcn_mfma_scale_f32_16x16x128_f8f6f4(
            kf[kg], qf, acc[kg][qg], 0, 0, 0, 0x7F7F7F7F, 0, 0x7F7F7F7F);
    }
  }

  // ---- E = exp2(S*scale) ----
#pragma unroll
  for (int kg = 0; kg < 4; ++kg)
#pragma unroll
    for (int qg = 0; qg < 4; ++qg)
#pragma unroll
      for (int j2 = 0; j2 < 4; ++j2)
        acc[kg][qg][j2] = exp2f(acc[kg][qg][j2] * EXP2_SCALE);

  // ---- rowsums (q-rows): in-thread over kg,j2 (15 adds), fold over lhi ----
  float rs[4];
#pragma unroll
  for (int qg = 0; qg < 4; ++qg) {
    f32x4 s4 = (acc[0][qg] + acc[1][qg]) + (acc[2][qg] + acc[3][qg]);
    float v = (s4[0] + s4[1]) + (s4[2] + s4[3]);
    v += __shfl_xor(v, 16);
    v += __shfl_xor(v, 32);
    rs[qg] = v;   // full 64-col sum for row (qg, l15), replicated over lhi
  }
  {
    float val = (lhi == 0) ? rs[0] : (lhi == 1) ? rs[1] : (lhi == 2) ? rs[2] : rs[3];
    RS[(wr * 64 + lhi * 16 + l15) * 3 + wc] = val;
  }

  // ---- colsums: in-thread over qg, then 4-stage full-16-lane fold ----
  // c[kg][j2]; final lane l15 holds kcol bits: j2 = l15&3, kg = l15>>2.
  float c[4][4];
#pragma unroll
  for (int kg = 0; kg < 4; ++kg)
#pragma unroll
    for (int j2 = 0; j2 < 4; ++j2)
      c[kg][j2] = (acc[kg][0][j2] + acc[kg][1][j2]) +
                  (acc[kg][2][j2] + acc[kg][3][j2]);
  const bool b0 = (l15 & 1), b1 = (l15 & 2), b2 = (l15 & 4), b3 = (l15 & 8);
  // stage 1 (xor 1): fold j2 bit0 -> d[kg][j2hi]
  float d[4][2];
#pragma unroll
  for (int kg = 0; kg < 4; ++kg) {
#pragma unroll
    for (int jh = 0; jh < 2; ++jh) {
      float t = b0 ? c[kg][jh * 2] : c[kg][jh * 2 + 1];
      float u = __shfl_xor(t, 1);
      d[kg][jh] = (b0 ? c[kg][jh * 2 + 1] : c[kg][jh * 2]) + u;
    }
  }
  // stage 2 (xor 2): fold j2 bit1 -> e[kg]
  float e[4];
#pragma unroll
  for (int kg = 0; kg < 4; ++kg) {
    float t = b1 ? d[kg][0] : d[kg][1];
    float u = __shfl_xor(t, 2);
    e[kg] = (b1 ? d[kg][1] : d[kg][0]) + u;
  }
  // stage 3 (xor 4): fold kg bit0 -> g01, g23
  float g01, g23;
  {
    float t, u;
    t = b2 ? e[0] : e[1]; u = __shfl_xor(t, 4); g01 = (b2 ? e[1] : e[0]) + u;
    t = b2 ? e[2] : e[3]; u = __shfl_xor(t, 4); g23 = (b2 ? e[3] : e[2]) + u;
  }
  // stage 4 (xor 8): fold kg bit1 -> f
  float f;
  {
    float t = b3 ? g01 : g23;
    float u = __shfl_xor(t, 8);
    f = (b3 ? g23 : g01) + u;
  }
  // lane (l15, lhi): kcol = wc*64 + (l15>>2)*16 + lhi*4 + (l15&3) — all distinct
  CS[(wc * 64 + (l15 >> 2) * 16 + lhi * 4 + (l15 & 3)) * 3 + wr] = f;
  __syncthreads();

  if (tid < 128) {
    RowP[(size_t)cb * NB + brow + tid] = RS[tid * 3 + 0] + RS[tid * 3 + 1];
  } else {
    const int t = tid - 128;
    ColP[(size_t)rb * NB + bcol + t] = CS[t * 3 + 0] + CS[t * 3 + 1];
  }
}

// ---------------- kernel 3: sum partials + final scalar loss ----------------
__global__ __launch_bounds__(256) void loss_kernel(
    const float* __restrict__ diag, const float* __restrict__ RowP,
    const float* __restrict__ ColP, float* __restrict__ out) {
  const int i = blockIdx.x * 256 + threadIdx.x;   // 32 blocks x 256 = 8192
  float rs = 0.f, cs = 0.f;
#pragma unroll 8
  for (int j = 0; j < 64; ++j) {
    rs += RowP[(size_t)j * NB + i];
    cs += ColP[(size_t)j * NB + i];
  }
  const float d = diag[i];
  float acc = -__logf(d / rs + EPS) - __logf(d / cs + EPS);
#pragma unroll
  for (int m = 1; m < 64; m <<= 1) acc += __shfl_xor(acc, m);
  __shared__ float ls[4];
  const int wave = threadIdx.x >> 6;
  if ((threadIdx.x & 63) == 0) ls[wave] = acc;
  __syncthreads();
  if (threadIdx.x == 0)
    atomicAdd(out, (ls[0] + ls[1] + ls[2] + ls[3]) * (1.0f / NB));
}

extern "C" void kernel_launch(void* const* d_in, const int* in_sizes, int n_in,
                              void* d_out, int out_size, void* d_ws, size_t ws_size,
                              hipStream_t stream) {
  const float* q = (const float*)d_in[0];
  const float* k = (const float*)d_in[1];
  char* ws = (char*)d_ws;
  uint*  qp   = (uint*)ws;                                      // 2 MB packed
  uint*  kp   = (uint*)(ws + (size_t)NB * ND);                  // 2 MB packed
  float* diag = (float*)(ws + (size_t)2 * NB * ND);             // 32 KB
  float* RowP = diag + NB;                                      // 2 MB
  float* ColP = RowP + 64 * NB;                                 // 2 MB
  float* out  = (float*)d_out;

  norm_pack_kernel<<<NB / 16, 1024, 0, stream>>>(q, k, qp, kp, diag, out);
  gemm_exp_reduce_kernel<<<dim3(64, 64), 256, 0, stream>>>(qp, kp, RowP, ColP);
  loss_kernel<<<32, 256, 0, stream>>>(diag, RowP, ColP, out);
}